// Round 4
// baseline (20088.075 us; speedup 1.0000x reference)
//
#include <hip/hip_runtime.h>
#include <hip/hip_bf16.h>
#include <cstdint>
#include <cstddef>

// 3-layer LSTM (T=128, B=256, IN=512, H=1024/1024/512) — persistent kernel, round 4.
// vs round 3:
//  - ONE grid barrier per timestep: phase(t) = { l2(t), l3(t-1), l1(t+1) } (l3 lags a step)
//  - fully-unrolled K-loops, ring depth 8, compile-time A1/A2 select,
//    ds_read b-frags at immediate offsets (bstride now a template constant;
//    l3 du>=2 lanes read duplicate slots — results unused by epilogue shuffles)

typedef __attribute__((ext_vector_type(8))) short short8;
typedef __attribute__((ext_vector_type(4))) short short4v;
typedef __attribute__((ext_vector_type(2))) short short2v;
typedef __attribute__((ext_vector_type(4))) float floatx4;

#define NBLK 256
#define NTHR 1024

// ---------------- helpers ----------------
__device__ __forceinline__ float fsig(float x) {
    x = fminf(fmaxf(x, -30.f), 30.f);
    return 1.f / (1.f + __expf(-x));
}
__device__ __forceinline__ float ftanh(float x) {
    x = fminf(fmaxf(x, -15.f), 15.f);
    float e = __expf(2.f * x);
    return (e - 1.f) / (e + 1.f);
}

__device__ __forceinline__ void grid_sync(int* cnt, int* gen) {
    __syncthreads();
    if (threadIdx.x == 0) {
        __threadfence();
        int g = __hip_atomic_load(gen, __ATOMIC_RELAXED, __HIP_MEMORY_SCOPE_AGENT);
        int a = __hip_atomic_fetch_add(cnt, 1, __ATOMIC_ACQ_REL, __HIP_MEMORY_SCOPE_AGENT);
        if (a == NBLK - 1) {
            __hip_atomic_store(cnt, 0, __ATOMIC_RELAXED, __HIP_MEMORY_SCOPE_AGENT);
            __hip_atomic_fetch_add(gen, 1, __ATOMIC_RELEASE, __HIP_MEMORY_SCOPE_AGENT);
        } else {
            while (__hip_atomic_load(gen, __ATOMIC_ACQUIRE, __HIP_MEMORY_SCOPE_AGENT) == g)
                __builtin_amdgcn_s_sleep(4);
        }
        __threadfence();
    }
    __syncthreads();
}

// ---------------- pack kernels ----------------
// Frag-ordered weight pack: dst[b][kc][slot] of short8.
// UPB=4: slot=lane: col=lane&15 (col=4*g+du), ksub=lane>>4. SLOTS=64.
// UPB=2: slot = ksub*8 + g*2 + du (du<2).                    SLOTS=32.
template<int K1, int K2, int H, int UPB>
__global__ void pack_frag_kernel(const float* __restrict__ Wih,
                                 const float* __restrict__ Whh,
                                 __hip_bfloat16* __restrict__ dst) {
    constexpr int SLOTS = (UPB == 4) ? 64 : 32;
    constexpr int NK = (K1 + K2) / 32;
    int idx = blockIdx.x * 256 + threadIdx.x;
    if (idx >= 256 * NK * SLOTS) return;
    int slot = idx % SLOTS;
    int kc = (idx / SLOTS) % NK;
    int b = idx / (SLOTS * NK);
    int du, g, ksub;
    if (UPB == 4) { du = slot & 3; g = (slot >> 2) & 3; ksub = slot >> 4; }
    else          { du = slot & 1; g = (slot >> 1) & 3; ksub = slot >> 3; }
    int unit = b * UPB + du;
    int j = g * H + unit;
    int k0 = kc * 32 + ksub * 8;
    __hip_bfloat16 tmp[8];
#pragma unroll
    for (int e = 0; e < 8; ++e) {
        int k = k0 + e;
        float v = (k < K1) ? Wih[(size_t)j * K1 + k] : Whh[(size_t)j * K2 + (k - K1)];
        tmp[e] = __float2bfloat16(v);
    }
    *(short8*)(dst + (size_t)idx * 8) = *(short8*)tmp;
}

__global__ void pack_bias_kernel(const float* __restrict__ a,
                                 const float* __restrict__ b,
                                 int n, float* __restrict__ out) {
    int i = blockIdx.x * 256 + threadIdx.x;
    if (i < n) out[i] = a[i] + b[i];
}

// x[t][row][512] fp32 -> xs[t][s][row][4] bf16 (slab4 layout). Coalesced writes.
__global__ void x_to_slab_kernel(const float* __restrict__ x,
                                 __hip_bfloat16* __restrict__ xs) {
    int idx = blockIdx.x * 256 + threadIdx.x;
    int j   = idx & 3;
    int row = (idx >> 2) & 255;
    int s   = (idx >> 10) & 127;
    int t   = idx >> 17;
    float v = x[((size_t)(t * 256 + row)) * 512 + s * 4 + j];
    xs[idx] = __float2bfloat16(v);
}

__global__ void zero_f32_kernel(float* p, int n) {
    int i = blockIdx.x * 256 + threadIdx.x;
    if (i < n) p[i] = 0.f;
}

__global__ void zero_i32_kernel(int* p, int n) {
    int i = blockIdx.x * 256 + threadIdx.x;
    if (i < n) p[i] = 0;
}

// ---------------- A-fragment loaders (compile-time k) ----------------
// slab4 frag at chunk k: elems k*8192 + ksub*2048 + row*4, halves +0/+1024
__device__ __forceinline__ short8 afrag4(const __hip_bfloat16* __restrict__ base, int k) {
    const __hip_bfloat16* p = base + (size_t)k * 8192;
    short4v lo = *(const short4v*)p;
    short4v hi = *(const short4v*)(p + 1024);
    return (short8){lo.x, lo.y, lo.z, lo.w, hi.x, hi.y, hi.z, hi.w};
}
// slab2 frag at chunk k: elems k*8192 + ksub*2048 + row*2, quarters +0/512/1024/1536
__device__ __forceinline__ short8 afrag2(const __hip_bfloat16* __restrict__ base, int k) {
    const __hip_bfloat16* p = base + (size_t)k * 8192;
    short2v q0 = *(const short2v*)p;
    short2v q1 = *(const short2v*)(p + 512);
    short2v q2 = *(const short2v*)(p + 1024);
    short2v q3 = *(const short2v*)(p + 1536);
    return (short8){q0.x, q0.y, q1.x, q1.y, q2.x, q2.y, q3.x, q3.y};
}

// ---------------- per-layer GEMM + fused cell ----------------
// Wave = 16-row M-tile, block's 16 gate-cols. B-frags from LDS at immediate
// offsets (BSTR compile-time). A ring depth 8, fully unrolled K-loop.
template<int NK1, int NK2, bool S2, int H, int UPB, int BSTR>
__device__ __forceinline__ void run_layer(
    const short8* __restrict__ ldsw, int bslot,
    const __hip_bfloat16* __restrict__ A1, const __hip_bfloat16* __restrict__ A2,
    float bias_lane, __hip_bfloat16* __restrict__ hs,
    float (&creg)[4], int blk, int lane, int wave,
    bool fin, float* __restrict__ ho, float* __restrict__ co)
{
    constexpr int NK = NK1 + NK2;
    constexpr int DEPTH = 8;
    const int col = lane & 15, ksub = lane >> 4;
    const int row = wave * 16 + col;
    const __hip_bfloat16* __restrict__ a1 = A1 + ksub * 2048 + row * 4;
    const __hip_bfloat16* __restrict__ a2 = S2 ? (A2 + ksub * 2048 + row * 2)
                                               : (A2 + ksub * 2048 + row * 4);
    const short8* __restrict__ bp = ldsw + bslot;

    auto getfrag = [&](int k) -> short8 {
        if (k < NK1) return afrag4(a1, k);
        return S2 ? afrag2(a2, k - NK1) : afrag4(a2, k - NK1);
    };

    short8 rb[DEPTH];
#pragma unroll
    for (int i = 0; i < DEPTH; ++i) rb[i] = getfrag(i);

    floatx4 acc = {0.f, 0.f, 0.f, 0.f};
#pragma unroll
    for (int kc = 0; kc < NK; ++kc) {
        short8 b = bp[kc * BSTR];   // ds_read_b128 with immediate offset
        acc = __builtin_amdgcn_mfma_f32_16x16x32_bf16(rb[kc & (DEPTH - 1)], b, acc, 0, 0, 0);
        if (kc + DEPTH < NK)
            rb[kc & (DEPTH - 1)] = getfrag(kc + DEPTH);
    }

    // epilogue: C/D layout col=lane&15, row=(lane>>4)*4+r. Gates at cols 4*g+du.
    const int duc = ((col & 3) < UPB) ? (col & 3) : 0;
    const int sbase = ksub * 16 + duc;
    float avb[4];
#pragma unroll
    for (int r = 0; r < 4; ++r) avb[r] = acc[r] + bias_lane;
#pragma unroll
    for (int r = 0; r < 4; ++r) {
        float gI = __shfl(avb[r], sbase);
        float gF = __shfl(avb[r], sbase + 4);
        float gG = __shfl(avb[r], sbase + 8);
        float gO = __shfl(avb[r], sbase + 12);
        float i_ = fsig(gI), f_ = fsig(gF), gg = ftanh(gG), o_ = fsig(gO);
        float cn = f_ * creg[r] + i_ * gg;
        creg[r] = cn;
        float hn = o_ * ftanh(cn);
        if (col < UPB) {
            int orow = wave * 16 + ksub * 4 + r;
            hs[(size_t)blk * (256 * UPB) + orow * UPB + col] = __float2bfloat16(hn);
            if (fin) {
                int unit = blk * UPB + col;
                ho[(size_t)orow * H + unit] = hn;
                co[(size_t)orow * H + unit] = cn;
            }
        }
    }
}

// ---------------- persistent kernel ----------------
__global__ __launch_bounds__(NTHR, 4) void lstm_persistent(
    const __hip_bfloat16* __restrict__ xs,
    const __hip_bfloat16* __restrict__ w1f,
    const __hip_bfloat16* __restrict__ w2f,
    const __hip_bfloat16* __restrict__ w3f,
    const float* __restrict__ bc1, const float* __restrict__ bc2, const float* __restrict__ bc3,
    __hip_bfloat16* __restrict__ h1b, __hip_bfloat16* __restrict__ h2b,
    __hip_bfloat16* __restrict__ h3b,
    float* __restrict__ out, int* sync_cnt, int* sync_gen)
{
    __shared__ short8 ldsw[8704];   // w1[0,3072) w2[3072,7168) w3[7168,8704)
    const int tid = threadIdx.x, blk = blockIdx.x;
    const int lane = tid & 63, wave = tid >> 6;

    {
        const short8* s1 = (const short8*)w1f + (size_t)blk * 3072;
        for (int i = tid; i < 3072; i += NTHR) ldsw[i] = s1[i];
        const short8* s2 = (const short8*)w2f + (size_t)blk * 4096;
        for (int i = tid; i < 4096; i += NTHR) ldsw[3072 + i] = s2[i];
        const short8* s3 = (const short8*)w3f + (size_t)blk * 1536;
        for (int i = tid; i < 1536; i += NTHR) ldsw[7168 + i] = s3[i];
    }
    __syncthreads();

    const int col = lane & 15, ksub = lane >> 4, du = col & 3, g = col >> 2;
    const int b1slot = lane;
    const int b2slot = 3072 + lane;
    const int b3slot = 7168 + ksub * 8 + g * 2 + (du & 1);  // du>=2 lanes duplicate — unused

    const float bl1 = bc1[g * 1024 + blk * 4 + du];
    const float bl2 = bc2[g * 1024 + blk * 4 + du];
    const float bl3 = bc3[g * 512 + blk * 2 + (du & 1)];

    float c1r[4] = {0.f, 0.f, 0.f, 0.f};
    float c2r[4] = {0.f, 0.f, 0.f, 0.f};
    float c3r[4] = {0.f, 0.f, 0.f, 0.f};

    float* h1o = out;
    float* c1o = out + 262144;
    float* h2o = out + 524288;
    float* c2o = out + 786432;
    float* h3o = out + 1048576;
    float* c3o = out + 1179648;

    // prologue: l1(0) — reads x(0), h1[1]=0; writes h1[0]
    run_layer<16, 32, false, 1024, 4, 64>(ldsw, b1slot,
        xs, h1b + 262144, bl1, h1b, c1r, blk, lane, wave, false, h1o, c1o);
    grid_sync(sync_cnt, sync_gen);

    // phase(t): l2(t), l3(t-1), l1(t+1); one barrier at end of phase
    for (int t = 0; t < 128; ++t) {
        const size_t cur = (size_t)(t & 1), prv = (size_t)((t + 1) & 1);
        // l2(t): [h1(t) | h2(t-1)] -> h2(t)
        run_layer<32, 32, false, 1024, 4, 64>(ldsw, b2slot,
            h1b + cur * 262144, h2b + prv * 262144, bl2,
            h2b + cur * 262144, c2r, blk, lane, wave, t == 127, h2o, c2o);
        // l3(t-1): [h2(t-1) | h3(t-2)] -> h3(t-1)
        if (t >= 1) {
            run_layer<32, 16, true, 512, 2, 32>(ldsw, b3slot,
                h2b + prv * 262144, h3b + cur * 131072, bl3,
                h3b + prv * 131072, c3r, blk, lane, wave, false, h3o, c3o);
        }
        // l1(t+1): [x(t+1) | h1(t)] -> h1(t+1)
        if (t < 127) {
            run_layer<16, 32, false, 1024, 4, 64>(ldsw, b1slot,
                xs + (size_t)(t + 1) * 131072, h1b + cur * 262144, bl1,
                h1b + prv * 262144, c1r, blk, lane, wave, (t + 1) == 127, h1o, c1o);
        }
        grid_sync(sync_cnt, sync_gen);
    }

    // epilogue: l3(127): [h2(127)=buf1 | h3(126)=buf0] -> h3(127), final
    run_layer<32, 16, true, 512, 2, 32>(ldsw, b3slot,
        h2b + 262144, h3b, bl3, h3b + 131072, c3r, blk, lane, wave, true, h3o, c3o);
}

// ---------------- launch ----------------
extern "C" void kernel_launch(void* const* d_in, const int* in_sizes, int n_in,
                              void* d_out, int out_size, void* d_ws, size_t ws_size,
                              hipStream_t stream) {
    const float* x    = (const float*)d_in[0];
    const float* Wih1 = (const float*)d_in[1];
    const float* Whh1 = (const float*)d_in[2];
    const float* bih1 = (const float*)d_in[3];
    const float* bhh1 = (const float*)d_in[4];
    const float* Wih2 = (const float*)d_in[5];
    const float* Whh2 = (const float*)d_in[6];
    const float* bih2 = (const float*)d_in[7];
    const float* bhh2 = (const float*)d_in[8];
    const float* Wih3 = (const float*)d_in[9];
    const float* Whh3 = (const float*)d_in[10];
    const float* bih3 = (const float*)d_in[11];
    const float* bhh3 = (const float*)d_in[12];
    float* out = (float*)d_out;

    char* p = (char*)d_ws;
    auto alloc = [&](size_t bytes) {
        char* r = p;
        p += (bytes + 255) & ~(size_t)255;
        return r;
    };
    __hip_bfloat16* xs  = (__hip_bfloat16*)alloc((size_t)128 * 128 * 256 * 4 * 2);
    __hip_bfloat16* w1f = (__hip_bfloat16*)alloc((size_t)256 * 3072 * 16);
    __hip_bfloat16* w2f = (__hip_bfloat16*)alloc((size_t)256 * 4096 * 16);
    __hip_bfloat16* w3f = (__hip_bfloat16*)alloc((size_t)256 * 1536 * 16);
    float* bc1 = (float*)alloc(4096 * 4);
    float* bc2 = (float*)alloc(4096 * 4);
    float* bc3 = (float*)alloc(2048 * 4);
    __hip_bfloat16* h1b = (__hip_bfloat16*)alloc((size_t)2 * 262144 * 2);
    __hip_bfloat16* h2b = (__hip_bfloat16*)alloc((size_t)2 * 262144 * 2);
    __hip_bfloat16* h3b = (__hip_bfloat16*)alloc((size_t)2 * 131072 * 2);
    int* syncp = (int*)alloc(256);

    auto blocks = [](int n) { return (n + 255) / 256; };

    pack_frag_kernel<512, 1024, 1024, 4><<<blocks(256 * 48 * 64), 256, 0, stream>>>(Wih1, Whh1, w1f);
    pack_frag_kernel<1024, 1024, 1024, 4><<<blocks(256 * 64 * 64), 256, 0, stream>>>(Wih2, Whh2, w2f);
    pack_frag_kernel<1024, 512, 512, 2><<<blocks(256 * 48 * 32), 256, 0, stream>>>(Wih3, Whh3, w3f);
    pack_bias_kernel<<<blocks(4096), 256, 0, stream>>>(bih1, bhh1, 4096, bc1);
    pack_bias_kernel<<<blocks(4096), 256, 0, stream>>>(bih2, bhh2, 4096, bc2);
    pack_bias_kernel<<<blocks(2048), 256, 0, stream>>>(bih3, bhh3, 2048, bc3);
    x_to_slab_kernel<<<blocks(128 * 256 * 512), 256, 0, stream>>>(x, xs);
    zero_f32_kernel<<<blocks(262144), 256, 0, stream>>>((float*)h1b, 262144);
    zero_f32_kernel<<<blocks(262144), 256, 0, stream>>>((float*)h2b, 262144);
    zero_f32_kernel<<<blocks(131072), 256, 0, stream>>>((float*)h3b, 131072);
    zero_i32_kernel<<<1, 256, 0, stream>>>(syncp, 64);

    lstm_persistent<<<NBLK, NTHR, 0, stream>>>(xs, w1f, w2f, w3f, bc1, bc2, bc3,
                                               h1b, h2b, h3b, out, syncp, syncp + 1);
}

// Round 5
// 8542.654 us; speedup vs baseline: 2.3515x; 2.3515x over previous
//
#include <hip/hip_runtime.h>
#include <hip/hip_bf16.h>
#include <cstdint>
#include <cstddef>

// 3-layer LSTM (T=128, B=256, IN=512, H=1024/1024/512) — persistent kernel, round 5.
// = round-3 run_layer (depth-4 ring, unroll 4, runtime LDS offsets — proven 64-VGPR,
//   no spills) + round-4 one-barrier-per-step pipeline (proven correct) +
//   two-level monotonic grid barrier (8x32 padded group counters -> master -> gen).
// Round-4 lesson: full unroll + depth-8 ring + per-chunk materialized 64-bit addrs
// spilled to scratch (FETCH/WRITE 12.1/12.9 GB). Do not reintroduce.

typedef __attribute__((ext_vector_type(8))) short short8;
typedef __attribute__((ext_vector_type(4))) short short4v;
typedef __attribute__((ext_vector_type(2))) short short2v;
typedef __attribute__((ext_vector_type(4))) float floatx4;

#define NBLK 256
#define NTHR 1024

// ---------------- helpers ----------------
__device__ __forceinline__ float fsig(float x) {
    x = fminf(fmaxf(x, -30.f), 30.f);
    return 1.f / (1.f + __expf(-x));
}
__device__ __forceinline__ float ftanh(float x) {
    x = fminf(fmaxf(x, -15.f), 15.f);
    float e = __expf(2.f * x);
    return (e - 1.f) / (e + 1.f);
}

// Two-level monotonic barrier: groups of 32 blocks (grp = blk & 7) arrive on
// padded per-group counters; group-closers bump master; 8th closer bumps gen.
// Monotonic counters (no reset race). Layout in ints: gcnt[g*64], mid@512, gen@576.
__device__ __forceinline__ void grid_sync(int* sy) {
    __syncthreads();
    if (threadIdx.x == 0) {
        __threadfence();
        int* gen = sy + 576;
        int g = __hip_atomic_load(gen, __ATOMIC_RELAXED, __HIP_MEMORY_SCOPE_AGENT);
        int grp = blockIdx.x & 7;
        int a = __hip_atomic_fetch_add(sy + grp * 64, 1, __ATOMIC_ACQ_REL, __HIP_MEMORY_SCOPE_AGENT);
        if (((a + 1) & 31) == 0) {
            int m = __hip_atomic_fetch_add(sy + 512, 1, __ATOMIC_ACQ_REL, __HIP_MEMORY_SCOPE_AGENT);
            if (((m + 1) & 7) == 0)
                __hip_atomic_fetch_add(gen, 1, __ATOMIC_RELEASE, __HIP_MEMORY_SCOPE_AGENT);
        }
        while (__hip_atomic_load(gen, __ATOMIC_ACQUIRE, __HIP_MEMORY_SCOPE_AGENT) == g)
            __builtin_amdgcn_s_sleep(2);
        __threadfence();
    }
    __syncthreads();
}

// ---------------- pack kernels ----------------
// Frag-ordered weight pack: dst[b][kc][slot] of short8.
// UPB=4: slot=lane: col=lane&15 (col=4*g+du), ksub=lane>>4. SLOTS=64.
// UPB=2: slot = ksub*8 + g*2 + du (du<2).                    SLOTS=32.
template<int K1, int K2, int H, int UPB>
__global__ void pack_frag_kernel(const float* __restrict__ Wih,
                                 const float* __restrict__ Whh,
                                 __hip_bfloat16* __restrict__ dst) {
    constexpr int SLOTS = (UPB == 4) ? 64 : 32;
    constexpr int NK = (K1 + K2) / 32;
    int idx = blockIdx.x * 256 + threadIdx.x;
    if (idx >= 256 * NK * SLOTS) return;
    int slot = idx % SLOTS;
    int kc = (idx / SLOTS) % NK;
    int b = idx / (SLOTS * NK);
    int du, g, ksub;
    if (UPB == 4) { du = slot & 3; g = (slot >> 2) & 3; ksub = slot >> 4; }
    else          { du = slot & 1; g = (slot >> 1) & 3; ksub = slot >> 3; }
    int unit = b * UPB + du;
    int j = g * H + unit;
    int k0 = kc * 32 + ksub * 8;
    __hip_bfloat16 tmp[8];
#pragma unroll
    for (int e = 0; e < 8; ++e) {
        int k = k0 + e;
        float v = (k < K1) ? Wih[(size_t)j * K1 + k] : Whh[(size_t)j * K2 + (k - K1)];
        tmp[e] = __float2bfloat16(v);
    }
    *(short8*)(dst + (size_t)idx * 8) = *(short8*)tmp;
}

__global__ void pack_bias_kernel(const float* __restrict__ a,
                                 const float* __restrict__ b,
                                 int n, float* __restrict__ out) {
    int i = blockIdx.x * 256 + threadIdx.x;
    if (i < n) out[i] = a[i] + b[i];
}

// x[t][row][512] fp32 -> xs[t][s][row][4] bf16 (slab4 layout). Coalesced writes.
__global__ void x_to_slab_kernel(const float* __restrict__ x,
                                 __hip_bfloat16* __restrict__ xs) {
    int idx = blockIdx.x * 256 + threadIdx.x;
    int j   = idx & 3;
    int row = (idx >> 2) & 255;
    int s   = (idx >> 10) & 127;
    int t   = idx >> 17;
    float v = x[((size_t)(t * 256 + row)) * 512 + s * 4 + j];
    xs[idx] = __float2bfloat16(v);
}

__global__ void zero_f32_kernel(float* p, int n) {
    int i = blockIdx.x * 256 + threadIdx.x;
    if (i < n) p[i] = 0.f;
}

__global__ void zero_i32_kernel(int* p, int n) {
    int i = blockIdx.x * 256 + threadIdx.x;
    if (i < n) p[i] = 0;
}

// ---------------- A-fragment loaders (uniform chunk index) ----------------
// slab4 frag at chunk k: base + k*8192, halves +0/+1024
__device__ __forceinline__ short8 afrag4(const __hip_bfloat16* __restrict__ base, int k) {
    const __hip_bfloat16* p = base + (size_t)k * 8192;
    short4v lo = *(const short4v*)p;
    short4v hi = *(const short4v*)(p + 1024);
    return (short8){lo.x, lo.y, lo.z, lo.w, hi.x, hi.y, hi.z, hi.w};
}
// slab2 frag at chunk k: base + k*8192, quarters +0/512/1024/1536
__device__ __forceinline__ short8 afrag2(const __hip_bfloat16* __restrict__ base, int k) {
    const __hip_bfloat16* p = base + (size_t)k * 8192;
    short2v q0 = *(const short2v*)p;
    short2v q1 = *(const short2v*)(p + 512);
    short2v q2 = *(const short2v*)(p + 1024);
    short2v q3 = *(const short2v*)(p + 1536);
    return (short8){q0.x, q0.y, q1.x, q1.y, q2.x, q2.y, q3.x, q3.y};
}

// ---------------- per-layer GEMM + fused cell (round-3 structure) ----------------
template<int NK1, int NK2, bool S2, int H, int UPB>
__device__ __forceinline__ void run_layer(
    const short8* __restrict__ ldsw, int bslot, int bstride,
    const __hip_bfloat16* __restrict__ A1, const __hip_bfloat16* __restrict__ A2,
    float bias_lane, __hip_bfloat16* __restrict__ hs,
    float (&creg)[4], int blk, int lane, int wave,
    bool fin, float* __restrict__ ho, float* __restrict__ co)
{
    constexpr int NK = NK1 + NK2;
    const int col = lane & 15, ksub = lane >> 4;
    const int row = wave * 16 + col;
    const __hip_bfloat16* __restrict__ a1 = A1 + ksub * 2048 + row * 4;
    const __hip_bfloat16* __restrict__ a2 = S2 ? (A2 + ksub * 2048 + row * 2)
                                               : (A2 + ksub * 2048 + row * 4);

    short8 rb[4];
#pragma unroll
    for (int i = 0; i < 4; ++i)      // NK1 >= 16 always: first 4 from A1
        rb[i] = afrag4(a1, i);

    floatx4 acc = {0.f, 0.f, 0.f, 0.f};
#pragma unroll 4
    for (int kc = 0; kc < NK; ++kc) {
        short8 b = ldsw[bslot + kc * bstride];
        acc = __builtin_amdgcn_mfma_f32_16x16x32_bf16(rb[kc & 3], b, acc, 0, 0, 0);
        int kn = kc + 4;
        if (kn < NK) {
            rb[kc & 3] = (kn < NK1) ? afrag4(a1, kn)
                                    : (S2 ? afrag2(a2, kn - NK1) : afrag4(a2, kn - NK1));
        }
    }

    // epilogue: C/D layout col=lane&15, row=(lane>>4)*4+r. Gates at cols 4*g+du.
    const int duc = ((col & 3) < UPB) ? (col & 3) : 0;
    const int sbase = ksub * 16 + duc;
    float avb[4];
#pragma unroll
    for (int r = 0; r < 4; ++r) avb[r] = acc[r] + bias_lane;
#pragma unroll
    for (int r = 0; r < 4; ++r) {
        float gI = __shfl(avb[r], sbase);
        float gF = __shfl(avb[r], sbase + 4);
        float gG = __shfl(avb[r], sbase + 8);
        float gO = __shfl(avb[r], sbase + 12);
        float i_ = fsig(gI), f_ = fsig(gF), gg = ftanh(gG), o_ = fsig(gO);
        float cn = f_ * creg[r] + i_ * gg;
        creg[r] = cn;
        float hn = o_ * ftanh(cn);
        if (col < UPB) {
            int orow = wave * 16 + ksub * 4 + r;
            hs[(size_t)blk * (256 * UPB) + orow * UPB + col] = __float2bfloat16(hn);
            if (fin) {
                int unit = blk * UPB + col;
                ho[(size_t)orow * H + unit] = hn;
                co[(size_t)orow * H + unit] = cn;
            }
        }
    }
}

// ---------------- persistent kernel ----------------
__global__ __launch_bounds__(NTHR, 4) void lstm_persistent(
    const __hip_bfloat16* __restrict__ xs,
    const __hip_bfloat16* __restrict__ w1f,
    const __hip_bfloat16* __restrict__ w2f,
    const __hip_bfloat16* __restrict__ w3f,
    const float* __restrict__ bc1, const float* __restrict__ bc2, const float* __restrict__ bc3,
    __hip_bfloat16* __restrict__ h1b, __hip_bfloat16* __restrict__ h2b,
    __hip_bfloat16* __restrict__ h3b,
    float* __restrict__ out, int* syncp)
{
    __shared__ short8 ldsw[8704];   // w1[0,3072) w2[3072,7168) w3[7168,8704)
    const int tid = threadIdx.x, blk = blockIdx.x;
    const int lane = tid & 63, wave = tid >> 6;

    {
        const short8* s1 = (const short8*)w1f + (size_t)blk * 3072;
        for (int i = tid; i < 3072; i += NTHR) ldsw[i] = s1[i];
        const short8* s2 = (const short8*)w2f + (size_t)blk * 4096;
        for (int i = tid; i < 4096; i += NTHR) ldsw[3072 + i] = s2[i];
        const short8* s3 = (const short8*)w3f + (size_t)blk * 1536;
        for (int i = tid; i < 1536; i += NTHR) ldsw[7168 + i] = s3[i];
    }
    __syncthreads();

    const int col = lane & 15, ksub = lane >> 4, du = col & 3, g = col >> 2;
    const int b1slot = lane;
    const int b2slot = 3072 + lane;
    const int b3slot = 7168 + ksub * 8 + g * 2 + (du & 1);  // du>=2 lanes duplicate — unused

    const float bl1 = bc1[g * 1024 + blk * 4 + du];
    const float bl2 = bc2[g * 1024 + blk * 4 + du];
    const float bl3 = bc3[g * 512 + blk * 2 + (du & 1)];

    float c1r[4] = {0.f, 0.f, 0.f, 0.f};
    float c2r[4] = {0.f, 0.f, 0.f, 0.f};
    float c3r[4] = {0.f, 0.f, 0.f, 0.f};

    float* h1o = out;
    float* c1o = out + 262144;
    float* h2o = out + 524288;
    float* c2o = out + 786432;
    float* h3o = out + 1048576;
    float* c3o = out + 1179648;

    // prologue: l1(0) — reads x(0), h1[1]=0; writes h1[0]
    run_layer<16, 32, false, 1024, 4>(ldsw, b1slot, 64,
        xs, h1b + 262144, bl1, h1b, c1r, blk, lane, wave, false, h1o, c1o);
    grid_sync(syncp);

    // phase(t): l2(t), l3(t-1), l1(t+1); one barrier per phase
    for (int t = 0; t < 128; ++t) {
        const size_t cur = (size_t)(t & 1), prv = (size_t)((t + 1) & 1);
        // l2(t): [h1(t) | h2(t-1)] -> h2(t)
        run_layer<32, 32, false, 1024, 4>(ldsw, b2slot, 64,
            h1b + cur * 262144, h2b + prv * 262144, bl2,
            h2b + cur * 262144, c2r, blk, lane, wave, t == 127, h2o, c2o);
        // l3(t-1): [h2(t-1) | h3(t-2)] -> h3(t-1)
        if (t >= 1) {
            run_layer<32, 16, true, 512, 2>(ldsw, b3slot, 32,
                h2b + prv * 262144, h3b + cur * 131072, bl3,
                h3b + prv * 131072, c3r, blk, lane, wave, false, h3o, c3o);
        }
        // l1(t+1): [x(t+1) | h1(t)] -> h1(t+1)
        if (t < 127) {
            run_layer<16, 32, false, 1024, 4>(ldsw, b1slot, 64,
                xs + (size_t)(t + 1) * 131072, h1b + cur * 262144, bl1,
                h1b + prv * 262144, c1r, blk, lane, wave, (t + 1) == 127, h1o, c1o);
        }
        grid_sync(syncp);
    }

    // epilogue: l3(127): [h2(127)=buf1 | h3(126)=buf0] -> h3(127), final
    run_layer<32, 16, true, 512, 2>(ldsw, b3slot, 32,
        h2b + 262144, h3b, bl3, h3b + 131072, c3r, blk, lane, wave, true, h3o, c3o);
}

// ---------------- launch ----------------
extern "C" void kernel_launch(void* const* d_in, const int* in_sizes, int n_in,
                              void* d_out, int out_size, void* d_ws, size_t ws_size,
                              hipStream_t stream) {
    const float* x    = (const float*)d_in[0];
    const float* Wih1 = (const float*)d_in[1];
    const float* Whh1 = (const float*)d_in[2];
    const float* bih1 = (const float*)d_in[3];
    const float* bhh1 = (const float*)d_in[4];
    const float* Wih2 = (const float*)d_in[5];
    const float* Whh2 = (const float*)d_in[6];
    const float* bih2 = (const float*)d_in[7];
    const float* bhh2 = (const float*)d_in[8];
    const float* Wih3 = (const float*)d_in[9];
    const float* Whh3 = (const float*)d_in[10];
    const float* bih3 = (const float*)d_in[11];
    const float* bhh3 = (const float*)d_in[12];
    float* out = (float*)d_out;

    char* p = (char*)d_ws;
    auto alloc = [&](size_t bytes) {
        char* r = p;
        p += (bytes + 255) & ~(size_t)255;
        return r;
    };
    __hip_bfloat16* xs  = (__hip_bfloat16*)alloc((size_t)128 * 128 * 256 * 4 * 2);
    __hip_bfloat16* w1f = (__hip_bfloat16*)alloc((size_t)256 * 3072 * 16);
    __hip_bfloat16* w2f = (__hip_bfloat16*)alloc((size_t)256 * 4096 * 16);
    __hip_bfloat16* w3f = (__hip_bfloat16*)alloc((size_t)256 * 1536 * 16);
    float* bc1 = (float*)alloc(4096 * 4);
    float* bc2 = (float*)alloc(4096 * 4);
    float* bc3 = (float*)alloc(2048 * 4);
    __hip_bfloat16* h1b = (__hip_bfloat16*)alloc((size_t)2 * 262144 * 2);
    __hip_bfloat16* h2b = (__hip_bfloat16*)alloc((size_t)2 * 262144 * 2);
    __hip_bfloat16* h3b = (__hip_bfloat16*)alloc((size_t)2 * 131072 * 2);
    int* syncp = (int*)alloc(4096);

    auto blocks = [](int n) { return (n + 255) / 256; };

    pack_frag_kernel<512, 1024, 1024, 4><<<blocks(256 * 48 * 64), 256, 0, stream>>>(Wih1, Whh1, w1f);
    pack_frag_kernel<1024, 1024, 1024, 4><<<blocks(256 * 64 * 64), 256, 0, stream>>>(Wih2, Whh2, w2f);
    pack_frag_kernel<1024, 512, 512, 2><<<blocks(256 * 48 * 32), 256, 0, stream>>>(Wih3, Whh3, w3f);
    pack_bias_kernel<<<blocks(4096), 256, 0, stream>>>(bih1, bhh1, 4096, bc1);
    pack_bias_kernel<<<blocks(4096), 256, 0, stream>>>(bih2, bhh2, 4096, bc2);
    pack_bias_kernel<<<blocks(2048), 256, 0, stream>>>(bih3, bhh3, 2048, bc3);
    x_to_slab_kernel<<<blocks(128 * 256 * 512), 256, 0, stream>>>(x, xs);
    zero_f32_kernel<<<blocks(262144), 256, 0, stream>>>((float*)h1b, 262144);
    zero_f32_kernel<<<blocks(262144), 256, 0, stream>>>((float*)h2b, 262144);
    zero_f32_kernel<<<blocks(131072), 256, 0, stream>>>((float*)h3b, 131072);
    zero_i32_kernel<<<1, 1024, 0, stream>>>(syncp, 1024);

    lstm_persistent<<<NBLK, NTHR, 0, stream>>>(xs, w1f, w2f, w3f, bc1, bc2, bc3,
                                               h1b, h2b, h3b, out, syncp);
}